// Round 16
// baseline (21577.040 us; speedup 1.0000x reference)
//
#include <hip/hip_runtime.h>

#define NPTS 16384
#define NB 4
#define MPER 4096
#define M_TOT 16384
#define CCH 32
#define HH1 128
#define HH2 256
#define HH3 256
#define KNB 33
#define NPAD 36
#define R2V (0.2f*0.2f)

// ws layout (bytes)
#define WS_IDX   0                    // 16384 int
#define WS_CNT   (WS_IDX + 65536)     // 16384 int
#define WS_NBR   (WS_CNT + 65536)     // 16384*36 int
#define WS_AGG   (WS_NBR + 2359296)   // 16384*256 f32

typedef float f32x2 __attribute__((ext_vector_type(2)));
typedef float f32x4 __attribute__((ext_vector_type(4)));

static __device__ __forceinline__ f32x2 pk_add(f32x2 a, f32x2 b) {
  f32x2 d; asm("v_pk_add_f32 %0, %1, %2" : "=v"(d) : "v"(a), "v"(b)); return d;
}
static __device__ __forceinline__ f32x2 pk_mul(f32x2 a, f32x2 b) {
  f32x2 d; asm("v_pk_mul_f32 %0, %1, %2" : "=v"(d) : "v"(a), "v"(b)); return d;
}

static __device__ __forceinline__ float get4(const float4& v, int j) {
  return j == 0 ? v.x : j == 1 ? v.y : j == 2 ? v.z : v.w;
}

#define FMA4(acc_, s_, w_) { (acc_).x += (s_)*(w_).x; (acc_).y += (s_)*(w_).y; (acc_).z += (s_)*(w_).z; (acc_).w += (s_)*(w_).w; }

// swizzled pair layout: pair q -> float element 4q + (q>>3)  (conflict-free:
// lanes in an 8-group are bank-stride-4, groups offset by 1 -> <=2 lanes/bank)
#define PAIR_ELEM(q_) (4 * (q_) + ((q_) >> 3))

// ---------------------------------------------------------------------------
// Kernel 1: farthest point sampling. r14's packed-f32 kernel (proven correct,
// absmax 0.015625) with its two measured costs removed: (a) 8-way LDS bank
// conflict from the 4q layout -> swizzled 4q+(q>>3); (b) per-iter address
// VALU -> per-thread byte bases precomputed once, group offsets as ds_read
// offset immediates. r15 showed the loop is ~72% VALU-issue-bound on active
// CUs; pk halves arithmetic, swizzle stops the conflict tax that ate r14.
// ---------------------------------------------------------------------------
__global__ __launch_bounds__(1024, 4) void fps_kernel(const float* __restrict__ pos,
    int* __restrict__ idxg, float* __restrict__ posd, float* __restrict__ batchf) {
  const int b = blockIdx.x;
  const int t = threadIdx.x;          // 0..1023
  const int base = b * NPTS;
  const int lane = t & 63, wv = t >> 6;  // wv 0..15
  __shared__ float xy[33792];         // 135168 B, swizzled {x0,x1,y0,y1} pairs
  __shared__ unsigned long long wslot[2][16];

  if (t < 16) { wslot[0][t] = 0ull; wslot[1][t] = 0ull; }

  f32x2 z0, z1, z2, z3, z4, z5, z6, z7;
  f32x2 md0, md1, md2, md3, md4, md5, md6, md7;

#define STG(G_, Z_) { \
    int q_ = (G_) * 1024 + t; int p_ = (base + 2 * q_) * 3; \
    f32x4 v_; \
    v_.x = pos[p_ + 0]; v_.z = pos[p_ + 1]; Z_.x = pos[p_ + 2]; \
    v_.y = pos[p_ + 3]; v_.w = pos[p_ + 4]; Z_.y = pos[p_ + 5]; \
    *(f32x4*)&xy[PAIR_ELEM(q_)] = v_; }
  STG(0, z0) STG(1, z1) STG(2, z2) STG(3, z3)
  STG(4, z4) STG(5, z5) STG(6, z6) STG(7, z7)

#define KEEPZ(V_) asm volatile("" : "+v"(V_));
  KEEPZ(z0) KEEPZ(z1) KEEPZ(z2) KEEPZ(z3)
  KEEPZ(z4) KEEPZ(z5) KEEPZ(z6) KEEPZ(z7)

  __syncthreads();   // wslot init + xy staging visible to all waves

  float nx = pos[base * 3 + 0], ny = pos[base * 3 + 1], nz = pos[base * 3 + 2];
  if (t == 0) {
    idxg[b * MPER] = base;
    posd[(b * MPER) * 3 + 0] = nx;
    posd[(b * MPER) * 3 + 1] = ny;
    posd[(b * MPER) * 3 + 2] = nz;
    batchf[b * MPER] = (float)b;
  }

  // per-thread swizzled LDS base pointers (group offsets are constants)
  const float* xyt = &xy[PAIR_ELEM(t)];   // pair q=G*1024+t -> xyt + 4224*G

  f32x2 nn_x, nn_y, nn_z;
  nn_x.x = nn_x.y = -nx; nn_y.x = nn_y.y = -ny; nn_z.x = nn_z.y = -nz;

  float bv; int bi;

#define DIST(G_, Z_, D2_) { \
    f32x4 v_ = *(const f32x4*)(xyt + 4224 * (G_)); \
    f32x2 px_; px_.x = v_.x; px_.y = v_.y; \
    f32x2 py_; py_.x = v_.z; py_.y = v_.w; \
    f32x2 dx_ = pk_add(px_, nn_x), dy_ = pk_add(py_, nn_y), dz_ = pk_add(Z_, nn_z); \
    D2_ = pk_add(pk_add(pk_mul(dx_, dx_), pk_mul(dy_, dy_)), pk_mul(dz_, dz_)); }

#define TREEBI { \
    float a0_ = fmaxf(md0.x, md0.y), a1_ = fmaxf(md1.x, md1.y); \
    float a2_ = fmaxf(md2.x, md2.y), a3_ = fmaxf(md3.x, md3.y); \
    float a4_ = fmaxf(md4.x, md4.y), a5_ = fmaxf(md5.x, md5.y); \
    float a6_ = fmaxf(md6.x, md6.y), a7_ = fmaxf(md7.x, md7.y); \
    bv = fmaxf(fmaxf(fmaxf(a0_, a1_), fmaxf(a2_, a3_)), \
               fmaxf(fmaxf(a4_, a5_), fmaxf(a6_, a7_))); \
    int nbi_ = 0; \
    if (md7.y == bv) nbi_ = 2 * (7 * 1024 + t) + 1; \
    if (md7.x == bv) nbi_ = 2 * (7 * 1024 + t); \
    if (md6.y == bv) nbi_ = 2 * (6 * 1024 + t) + 1; \
    if (md6.x == bv) nbi_ = 2 * (6 * 1024 + t); \
    if (md5.y == bv) nbi_ = 2 * (5 * 1024 + t) + 1; \
    if (md5.x == bv) nbi_ = 2 * (5 * 1024 + t); \
    if (md4.y == bv) nbi_ = 2 * (4 * 1024 + t) + 1; \
    if (md4.x == bv) nbi_ = 2 * (4 * 1024 + t); \
    if (md3.y == bv) nbi_ = 2 * (3 * 1024 + t) + 1; \
    if (md3.x == bv) nbi_ = 2 * (3 * 1024 + t); \
    if (md2.y == bv) nbi_ = 2 * (2 * 1024 + t) + 1; \
    if (md2.x == bv) nbi_ = 2 * (2 * 1024 + t); \
    if (md1.y == bv) nbi_ = 2 * (1 * 1024 + t) + 1; \
    if (md1.x == bv) nbi_ = 2 * (1 * 1024 + t); \
    if (md0.y == bv) nbi_ = 2 * t + 1; \
    if (md0.x == bv) nbi_ = 2 * t; \
    bi = nbi_; }

  // initial distances to point 0
  { f32x2 d2_;
    DIST(0, z0, d2_) md0 = d2_; DIST(1, z1, d2_) md1 = d2_;
    DIST(2, z2, d2_) md2 = d2_; DIST(3, z3, d2_) md3 = d2_;
    DIST(4, z4, d2_) md4 = d2_; DIST(5, z5, d2_) md5 = d2_;
    DIST(6, z6, d2_) md6 = d2_; DIST(7, z7, d2_) md7 = d2_; }
  TREEBI

  for (int m = 1; m < MPER; ++m) {
    const int p = m & 1;
    unsigned long long key = ((unsigned long long)m << 52)
        | ((unsigned long long)__float_as_uint(bv) << 20)
        | ((unsigned long long)(16383 - bi) << 6);
    atomicMax(&wslot[p][wv], key);
    __syncthreads();
    unsigned long long k = wslot[p][lane & 15];
#pragma unroll
    for (int off = 1; off <= 8; off <<= 1) {
      unsigned long long o = __shfl_xor(k, off, 64);
      if (o > k) k = o;
    }
    const int j = 16383 - (int)((k >> 6) & 0x3FFF);
    const int jq = j >> 1, jh = j & 1;
    const int je = PAIR_ELEM(jq);
    float njx = xy[je + jh];
    float njy = xy[je + 2 + jh];
    float njz = pos[(base + j) * 3 + 2];
    if (t == 0) {
      idxg[b * MPER + m] = base + j;
      posd[(b * MPER + m) * 3 + 0] = njx;
      posd[(b * MPER + m) * 3 + 1] = njy;
      posd[(b * MPER + m) * 3 + 2] = njz;
      batchf[b * MPER + m] = (float)b;
    }
    if (m < MPER - 1) {
      nn_x.x = nn_x.y = -njx; nn_y.x = nn_y.y = -njy; nn_z.x = nn_z.y = -njz;
      f32x2 d2_;
      DIST(0, z0, d2_) md0.x = fminf(md0.x, d2_.x); md0.y = fminf(md0.y, d2_.y);
      DIST(1, z1, d2_) md1.x = fminf(md1.x, d2_.x); md1.y = fminf(md1.y, d2_.y);
      DIST(2, z2, d2_) md2.x = fminf(md2.x, d2_.x); md2.y = fminf(md2.y, d2_.y);
      DIST(3, z3, d2_) md3.x = fminf(md3.x, d2_.x); md3.y = fminf(md3.y, d2_.y);
      DIST(4, z4, d2_) md4.x = fminf(md4.x, d2_.x); md4.y = fminf(md4.y, d2_.y);
      DIST(5, z5, d2_) md5.x = fminf(md5.x, d2_.x); md5.y = fminf(md5.y, d2_.y);
      DIST(6, z6, d2_) md6.x = fminf(md6.x, d2_.x); md6.y = fminf(md6.y, d2_.y);
      DIST(7, z7, d2_) md7.x = fminf(md7.x, d2_.x); md7.y = fminf(md7.y, d2_.y);
      TREEBI
    }
  }
}

// ---------------------------------------------------------------------------
// Kernel 2: radius ball query + select 33 nearest (lexicographic (d2, idx)).
// One wave per centroid, 4 centroids per block. Queue push via ballot+
// popcount (wave owns its queue exclusively -> no LDS atomics).
// ---------------------------------------------------------------------------
#define BQ_TILE 2048
#define BQ_CAP 1024
__global__ __launch_bounds__(256) void ballq_kernel(const float* __restrict__ pos,
    const int* __restrict__ idxg, int* __restrict__ nbr, int* __restrict__ cntsel) {
  __shared__ float xs[BQ_TILE], ys[BQ_TILE], zs[BQ_TILE];
  __shared__ float d2l[4 * BQ_CAP];
  __shared__ int   jl[4 * BQ_CAP];
  const int t = threadIdx.x, lane = t & 63, wv = t >> 6;
  const int c = blockIdx.x * 4 + wv;
  const int b = c >> 12;            // c / 4096
  const int cbase = b * NPTS;
  const int ci = idxg[c];
  const float cx = pos[ci * 3 + 0], cy = pos[ci * 3 + 1], cz = pos[ci * 3 + 2];
  int cnt = 0;                      // wave-uniform queue count (register)
  for (int T = 0; T < NPTS / BQ_TILE; ++T) {
    __syncthreads();
    for (int s = t; s < BQ_TILE; s += 256) {
      int p = cbase + T * BQ_TILE + s;
      xs[s] = pos[p * 3 + 0]; ys[s] = pos[p * 3 + 1]; zs[s] = pos[p * 3 + 2];
    }
    __syncthreads();
    for (int s = lane; s < BQ_TILE; s += 64) {
      float dx = xs[s] - cx, dy = ys[s] - cy, dz = zs[s] - cz;
      float d2 = __fadd_rn(__fadd_rn(__fmul_rn(dx, dx), __fmul_rn(dy, dy)), __fmul_rn(dz, dz));
      bool in = (d2 <= R2V);
      unsigned long long mask = __ballot(in);
      if (in) {
        int p = cnt + __popcll(mask & ((1ull << lane) - 1ull));
        if (p < BQ_CAP) { d2l[wv * BQ_CAP + p] = d2; jl[wv * BQ_CAP + p] = T * BQ_TILE + s; }
      }
      cnt += __popcll(mask);
    }
  }
  int n = min(cnt, BQ_CAP);
  int ks = min(KNB, n);
  float lv = -1.0f; int lj = -1;
  for (int it = 0; it < ks; ++it) {
    float mv = 3.4e38f; int mj = 0x7fffffff;
    for (int s = lane; s < n; s += 64) {
      float v = d2l[wv * BQ_CAP + s]; int j = jl[wv * BQ_CAP + s];
      bool newer = (v > lv) || (v == lv && j > lj);
      if (newer && (v < mv || (v == mv && j < mj))) { mv = v; mj = j; }
    }
#pragma unroll
    for (int off = 32; off >= 1; off >>= 1) {
      float ov = __shfl_xor(mv, off, 64);
      int   oj = __shfl_xor(mj, off, 64);
      if (ov < mv || (ov == mv && oj < mj)) { mv = ov; mj = oj; }
    }
    if (lane == 0) nbr[c * NPAD + it] = cbase + mj;
    lv = mv; lj = mj;
  }
  if (lane == 0) cntsel[c] = ks;
}

// ---------------------------------------------------------------------------
// Kernel 3: fused layer1 (35->128) + layer2 (128->256) + masked max-agg.
// 2 centroids per block (80 edge rows, rows >= cnt zero/masked), 320 threads.
// ---------------------------------------------------------------------------
__global__ __launch_bounds__(320) void fused_kernel(const float* __restrict__ x,
    const float* __restrict__ pos, const int* __restrict__ idxg,
    const int* __restrict__ nbr, const int* __restrict__ cnts,
    const float* __restrict__ lw1, const float* __restrict__ lb1,
    const float* __restrict__ lw2, const float* __restrict__ lb2,
    float* __restrict__ agg) {
  __shared__ float h1s[80 * 132];      // 42.2 KB
  __shared__ float wt[16 * 256];       // 16 KB (union: wx stage 32x128 in phase1)
  __shared__ float xr[80 * 36];        // 11.5 KB
  __shared__ float wr[4 * 128];        // lw1 rows 32..34 + lb1
  __shared__ float dpx[80], dpy[80], dpz[80];
  __shared__ int   jg[80];
  __shared__ float pcs[6];
  __shared__ int   cns[2];
  __shared__ unsigned aggL[512];
  const int t = threadIdx.x;
  const int c0 = blockIdx.x * 2;

  // phase 0: metadata + small weights + agg init
  if (t < 2) {
    int c = c0 + t; int ci = idxg[c];
    pcs[t * 3 + 0] = pos[ci * 3 + 0];
    pcs[t * 3 + 1] = pos[ci * 3 + 1];
    pcs[t * 3 + 2] = pos[ci * 3 + 2];
    cns[t] = cnts[c];
  }
  for (int i = t; i < 512; i += 320) {
    wr[i] = (i < 384) ? lw1[32 * 128 + i] : lb1[i - 384];
    aggL[i] = 0u;
  }
  __syncthreads();
  if (t < 80) {
    int r = t; int cc = (r >= 40) ? 1 : 0; int e = r - cc * 40;
    int j = -1;
    if (e < cns[cc]) {
      j = nbr[(c0 + cc) * NPAD + e];
      dpx[r] = pos[j * 3 + 0] - pcs[cc * 3 + 0];
      dpy[r] = pos[j * 3 + 1] - pcs[cc * 3 + 1];
      dpz[r] = pos[j * 3 + 2] - pcs[cc * 3 + 2];
    } else { dpx[r] = 0.f; dpy[r] = 0.f; dpz[r] = 0.f; }
    jg[r] = j;
  }
  __syncthreads();
  // stage x rows (zero for invalid) + wx (= lw1[0:32][:]) into wt
  for (int i = t; i < 640; i += 320) {
    int r = i >> 3, q = i & 7;
    int j = jg[r];
    float4 v = make_float4(0.f, 0.f, 0.f, 0.f);
    if (j >= 0) v = *(const float4*)&x[j * CCH + q * 4];
    *(float4*)&xr[r * 36 + q * 4] = v;
  }
  for (int i = t; i < 1024; i += 320) {
    *(float4*)&wt[i * 4] = *(const float4*)&lw1[i * 4];
  }
  __syncthreads();

  // phase 1: h1 = relu(xr@wx + dpos@wr + lb1). tile 4 rows x 8 cols per thread.
  {
    const int rg = t >> 4;      // 0..19
    const int og = t & 15;      // 0..15
    float4 a0[4], a1[4];
#pragma unroll
    for (int i = 0; i < 4; ++i) { a0[i] = make_float4(0, 0, 0, 0); a1[i] = make_float4(0, 0, 0, 0); }
#pragma unroll
    for (int kq = 0; kq < 8; ++kq) {
      float4 xv[4];
#pragma unroll
      for (int i = 0; i < 4; ++i) xv[i] = *(const float4*)&xr[(rg * 4 + i) * 36 + kq * 4];
#pragma unroll
      for (int kk = 0; kk < 4; ++kk) {
        float4 w0 = *(const float4*)&wt[(kq * 4 + kk) * 128 + og * 8];
        float4 w1 = *(const float4*)&wt[(kq * 4 + kk) * 128 + og * 8 + 4];
#pragma unroll
        for (int i = 0; i < 4; ++i) {
          float s = get4(xv[i], kk);
          FMA4(a0[i], s, w0);
          FMA4(a1[i], s, w1);
        }
      }
    }
#pragma unroll
    for (int i = 0; i < 4; ++i) {
      int r = rg * 4 + i;
      float dx = dpx[r], dy = dpy[r], dz = dpz[r];
#pragma unroll
      for (int j = 0; j < 8; ++j) {
        int o = og * 8 + j;
        float v = (j < 4) ? get4(a0[i], j) : get4(a1[i], j - 4);
        v = v + dx * wr[o];
        v = v + dy * wr[128 + o];
        v = v + dz * wr[256 + o];
        v = v + wr[384 + o];
        h1s[r * 132 + o] = fmaxf(v, 0.0f);
      }
    }
  }
  __syncthreads();

  // phase 2: h2 = h1s[80x128] @ lw2[128x256], k-tiles of 16, tile 8x8/thread
  const int og2 = t & 31;   // cols og2*8
  const int eg = t >> 5;    // rows eg*8
  float4 c0v[8], c1v[8];
#pragma unroll
  for (int i = 0; i < 8; ++i) { c0v[i] = make_float4(0, 0, 0, 0); c1v[i] = make_float4(0, 0, 0, 0); }
  for (int kt = 0; kt < 8; ++kt) {
    __syncthreads();
    for (int i = t; i < 1024; i += 320) {
      *(float4*)&wt[i * 4] = *(const float4*)&lw2[kt * 4096 + i * 4];
    }
    __syncthreads();
#pragma unroll
    for (int kq = 0; kq < 4; ++kq) {
      float4 h4[8];
#pragma unroll
      for (int i = 0; i < 8; ++i)
        h4[i] = *(const float4*)&h1s[(eg * 8 + i) * 132 + kt * 16 + kq * 4];
#pragma unroll
      for (int kk = 0; kk < 4; ++kk) {
        float4 wa = *(const float4*)&wt[(kq * 4 + kk) * 256 + og2 * 8];
        float4 wb = *(const float4*)&wt[(kq * 4 + kk) * 256 + og2 * 8 + 4];
#pragma unroll
        for (int i = 0; i < 8; ++i) {
          float hv = get4(h4[i], kk);
          FMA4(c0v[i], hv, wa);
          FMA4(c1v[i], hv, wb);
        }
      }
    }
  }

  // phase 3: bias + relu + masked max into LDS (uint bits, values >= 0)
  {
    int cc = (eg >= 5) ? 1 : 0;
    int ebase = eg * 8 - cc * 40;
    int n = cns[cc];
#pragma unroll
    for (int j = 0; j < 8; ++j) {
      int o = og2 * 8 + j;
      float bias = lb2[o];
      float mx = -1.0f;
#pragma unroll
      for (int i = 0; i < 8; ++i) {
        if (ebase + i < n) {
          float v = ((j < 4) ? get4(c0v[i], j) : get4(c1v[i], j - 4)) + bias;
          v = fmaxf(v, 0.0f);
          mx = fmaxf(mx, v);
        }
      }
      if (mx >= 0.0f) atomicMax(&aggL[cc * 256 + o], __float_as_uint(mx));
    }
  }
  __syncthreads();
  for (int i = t; i < 512; i += 320) {
    agg[c0 * 256 + i] = __uint_as_float(aggL[i]);
  }
}

// ---------------------------------------------------------------------------
// Kernel 4: out = relu(agg @ gw1 + gb1). 64 rows x 256 cols per block.
// ---------------------------------------------------------------------------
__global__ __launch_bounds__(256) void l3_kernel(const float* __restrict__ agg,
    const float* __restrict__ gw1, const float* __restrict__ gb1,
    float* __restrict__ out) {
  __shared__ float at[32 * 68];
  __shared__ float wt[32 * 256];
  const int t = threadIdx.x;
  const int row0 = blockIdx.x * 64;
  const int og = t & 31, rg = t >> 5;
  float4 c0v[8], c1v[8];
#pragma unroll
  for (int i = 0; i < 8; ++i) { c0v[i] = make_float4(0, 0, 0, 0); c1v[i] = make_float4(0, 0, 0, 0); }
  for (int kt = 0; kt < 8; ++kt) {
    __syncthreads();
    for (int i = t; i < 2048; i += 256) {
      int k = i & 31, r = i >> 5;
      at[k * 68 + r] = agg[(row0 + r) * 256 + kt * 32 + k];
    }
    for (int i = t; i < 2048; i += 256) {
      *(float4*)&wt[i * 4] = *(const float4*)&gw1[kt * 8192 + i * 4];
    }
    __syncthreads();
#pragma unroll
    for (int kq = 0; kq < 8; ++kq) {
#pragma unroll
      for (int kk = 0; kk < 4; ++kk) {
        int k = kq * 4 + kk;
        float4 av0 = *(const float4*)&at[k * 68 + rg * 8];
        float4 av1 = *(const float4*)&at[k * 68 + rg * 8 + 4];
        float4 wa = *(const float4*)&wt[k * 256 + og * 8];
        float4 wb = *(const float4*)&wt[k * 256 + og * 8 + 4];
#pragma unroll
        for (int i = 0; i < 8; ++i) {
          float hv = (i < 4) ? get4(av0, i) : get4(av1, i - 4);
          FMA4(c0v[i], hv, wa);
          FMA4(c1v[i], hv, wb);
        }
      }
    }
  }
  float4 b0 = *(const float4*)&gb1[og * 8];
  float4 b1 = *(const float4*)&gb1[og * 8 + 4];
#pragma unroll
  for (int i = 0; i < 8; ++i) {
    float4 v0, v1;
    v0.x = fmaxf(c0v[i].x + b0.x, 0.f); v0.y = fmaxf(c0v[i].y + b0.y, 0.f);
    v0.z = fmaxf(c0v[i].z + b0.z, 0.f); v0.w = fmaxf(c0v[i].w + b0.w, 0.f);
    v1.x = fmaxf(c1v[i].x + b1.x, 0.f); v1.y = fmaxf(c1v[i].y + b1.y, 0.f);
    v1.z = fmaxf(c1v[i].z + b1.z, 0.f); v1.w = fmaxf(c1v[i].w + b1.w, 0.f);
    int row = row0 + rg * 8 + i;
    *(float4*)&out[row * 256 + og * 8] = v0;
    *(float4*)&out[row * 256 + og * 8 + 4] = v1;
  }
}

extern "C" void kernel_launch(void* const* d_in, const int* in_sizes, int n_in,
                              void* d_out, int out_size, void* d_ws, size_t ws_size,
                              hipStream_t stream) {
  (void)in_sizes; (void)n_in; (void)out_size; (void)ws_size;
  const float* x   = (const float*)d_in[0];
  const float* pos = (const float*)d_in[1];
  const float* lw1 = (const float*)d_in[3];
  const float* lb1 = (const float*)d_in[4];
  const float* lw2 = (const float*)d_in[5];
  const float* lb2 = (const float*)d_in[6];
  const float* gw1 = (const float*)d_in[7];
  const float* gb1 = (const float*)d_in[8];

  char* ws = (char*)d_ws;
  int*   idxg   = (int*)(ws + WS_IDX);
  int*   cnts   = (int*)(ws + WS_CNT);
  int*   nbr    = (int*)(ws + WS_NBR);
  float* agg    = (float*)(ws + WS_AGG);

  float* out0   = (float*)d_out;
  float* posd   = out0 + (size_t)M_TOT * HH3;
  float* batchf = posd + (size_t)M_TOT * 3;

  fps_kernel<<<dim3(NB), dim3(1024), 0, stream>>>(pos, idxg, posd, batchf);
  ballq_kernel<<<dim3(M_TOT / 4), dim3(256), 0, stream>>>(pos, idxg, nbr, cnts);
  fused_kernel<<<dim3(M_TOT / 2), dim3(320), 0, stream>>>(x, pos, idxg, nbr, cnts,
                                                          lw1, lb1, lw2, lb2, agg);
  l3_kernel<<<dim3(M_TOT / 64), dim3(256), 0, stream>>>(agg, gw1, gb1, out0);
}

// Round 17
// 11223.456 us; speedup vs baseline: 1.9225x; 1.9225x over previous
//
#include <hip/hip_runtime.h>

#define NPTS 16384
#define NB 4
#define MPER 4096
#define M_TOT 16384
#define CCH 32
#define HH1 128
#define HH2 256
#define HH3 256
#define KNB 33
#define NPAD 36
#define R2V (0.2f*0.2f)

// ws layout (bytes)
#define WS_IDX   0                    // 16384 int
#define WS_CNT   (WS_IDX + 65536)     // 16384 int
#define WS_NBR   (WS_CNT + 65536)     // 16384*36 int
#define WS_AGG   (WS_NBR + 2359296)   // 16384*256 f32

static __device__ __forceinline__ float get4(const float4& v, int j) {
  return j == 0 ? v.x : j == 1 ? v.y : j == 2 ? v.z : v.w;
}

#define FMA4(acc_, s_, w_) { (acc_).x += (s_)*(w_).x; (acc_).y += (s_)*(w_).y; (acc_).z += (s_)*(w_).z; (acc_).w += (s_)*(w_).w; }

// ---------------------------------------------------------------------------
// Kernel 1: farthest point sampling — EXACT r11 structure (best measured:
// 9156us, zero bank conflicts). px,py in LDS float2; pz+mind in regs;
// 1024 thr, one barrier/iter, 16-wave LDS partials + shfl reduce.
// r8-r16 established this is a serial-critical-path floor; stop.
// ---------------------------------------------------------------------------
__global__ __launch_bounds__(1024, 4) void fps_kernel(const float* __restrict__ pos,
    int* __restrict__ idxg, float* __restrict__ posd, float* __restrict__ batchf) {
  const int b = blockIdx.x;
  const int t = threadIdx.x;          // 0..1023
  const int base = b * NPTS;
  const int lane = t & 63, wv = t >> 6;  // wv 0..15
  __shared__ float pxy[2 * NPTS];     // 131072 B: px,py interleaved
  __shared__ float bufV[2][16];
  __shared__ int   bufI[2][16];

  float4 pz0, pz1, pz2, pz3;
  float4 md0, md1, md2, md3;

#define STG1(C_, PZ_, I0_) { \
    int li_ = (I0_) + t; int p_ = base + li_; \
    float ax_ = pos[p_ * 3 + 0], ay_ = pos[p_ * 3 + 1]; \
    PZ_.C_ = pos[p_ * 3 + 2]; \
    *(float2*)&pxy[li_ * 2] = make_float2(ax_, ay_); }
#define STG4(PZ_, G_) \
    STG1(x, PZ_, ((G_)*4+0)*1024) \
    STG1(y, PZ_, ((G_)*4+1)*1024) \
    STG1(z, PZ_, ((G_)*4+2)*1024) \
    STG1(w, PZ_, ((G_)*4+3)*1024)

  STG4(pz0, 0) STG4(pz1, 1) STG4(pz2, 2) STG4(pz3, 3)

#define KEEP4(V_) asm volatile("" : "+v"((V_).x), "+v"((V_).y), "+v"((V_).z), "+v"((V_).w));
  KEEP4(pz0) KEEP4(pz1) KEEP4(pz2) KEEP4(pz3)

  float nx = pos[base * 3 + 0], ny = pos[base * 3 + 1], nz = pos[base * 3 + 2];
  if (t == 0) {
    idxg[b * MPER] = base;
    posd[(b * MPER) * 3 + 0] = nx;
    posd[(b * MPER) * 3 + 1] = ny;
    posd[(b * MPER) * 3 + 2] = nz;
    batchf[b * MPER] = (float)b;
  }

  float bv = -1.0f; int bi = 0;

#define UPD1(C_, PZ_, MD_, I0_, FIRST_) { \
    int li_ = (I0_) + t; \
    float2 xy_ = *(const float2*)&pxy[li_ * 2]; \
    float dx_ = xy_.x - nx, dy_ = xy_.y - ny, dz_ = PZ_.C_ - nz; \
    float d2_ = __fadd_rn(__fadd_rn(__fmul_rn(dx_, dx_), __fmul_rn(dy_, dy_)), __fmul_rn(dz_, dz_)); \
    float m_ = (FIRST_) ? d2_ : fminf(MD_.C_, d2_); MD_.C_ = m_; \
    if (m_ > bv) { bv = m_; bi = li_; } }
#define UPD4(PZ_, MD_, G_, FIRST_) \
    UPD1(x, PZ_, MD_, ((G_)*4+0)*1024, FIRST_) \
    UPD1(y, PZ_, MD_, ((G_)*4+1)*1024, FIRST_) \
    UPD1(z, PZ_, MD_, ((G_)*4+2)*1024, FIRST_) \
    UPD1(w, PZ_, MD_, ((G_)*4+3)*1024, FIRST_)

  UPD4(pz0, md0, 0, true) UPD4(pz1, md1, 1, true)
  UPD4(pz2, md2, 2, true) UPD4(pz3, md3, 3, true)

#pragma unroll
  for (int off = 32; off >= 1; off >>= 1) {
    float ov = __shfl_xor(bv, off, 64);
    int   oi = __shfl_xor(bi, off, 64);
    if (ov > bv || (ov == bv && oi < bi)) { bv = ov; bi = oi; }
  }

  for (int m = 1; m < MPER; ++m) {
    if (lane == 0) { bufV[m & 1][wv] = bv; bufI[m & 1][wv] = bi; }
    __syncthreads();
    float v = bufV[m & 1][lane & 15];
    int   j = bufI[m & 1][lane & 15];
#pragma unroll
    for (int off = 8; off >= 1; off >>= 1) {
      float ov = __shfl_xor(v, off, 64);
      int   oj = __shfl_xor(j, off, 64);
      if (ov > v || (ov == v && oj < j)) { v = ov; j = oj; }
    }
    nx = pos[(base + j) * 3 + 0];
    ny = pos[(base + j) * 3 + 1];
    nz = pos[(base + j) * 3 + 2];
    if (t == 0) {
      idxg[b * MPER + m] = base + j;
      posd[(b * MPER + m) * 3 + 0] = nx;
      posd[(b * MPER + m) * 3 + 1] = ny;
      posd[(b * MPER + m) * 3 + 2] = nz;
      batchf[b * MPER + m] = (float)b;
    }
    bv = -1.0f; bi = 0;
    UPD4(pz0, md0, 0, false) UPD4(pz1, md1, 1, false)
    UPD4(pz2, md2, 2, false) UPD4(pz3, md3, 3, false)
#pragma unroll
    for (int off = 32; off >= 1; off >>= 1) {
      float ov = __shfl_xor(bv, off, 64);
      int   oi = __shfl_xor(bi, off, 64);
      if (ov > bv || (ov == bv && oi < bi)) { bv = ov; bi = oi; }
    }
  }
}

// ---------------------------------------------------------------------------
// Kernel 2: radius ball query + select 33 nearest (lexicographic (d2, idx)).
// One wave per centroid, 4 centroids per block. Queue push via ballot+
// popcount (wave owns its queue exclusively -> no LDS atomics).
// ---------------------------------------------------------------------------
#define BQ_TILE 2048
#define BQ_CAP 1024
__global__ __launch_bounds__(256) void ballq_kernel(const float* __restrict__ pos,
    const int* __restrict__ idxg, int* __restrict__ nbr, int* __restrict__ cntsel) {
  __shared__ float xs[BQ_TILE], ys[BQ_TILE], zs[BQ_TILE];
  __shared__ float d2l[4 * BQ_CAP];
  __shared__ int   jl[4 * BQ_CAP];
  const int t = threadIdx.x, lane = t & 63, wv = t >> 6;
  const int c = blockIdx.x * 4 + wv;
  const int b = c >> 12;            // c / 4096
  const int cbase = b * NPTS;
  const int ci = idxg[c];
  const float cx = pos[ci * 3 + 0], cy = pos[ci * 3 + 1], cz = pos[ci * 3 + 2];
  int cnt = 0;                      // wave-uniform queue count (register)
  for (int T = 0; T < NPTS / BQ_TILE; ++T) {
    __syncthreads();
    for (int s = t; s < BQ_TILE; s += 256) {
      int p = cbase + T * BQ_TILE + s;
      xs[s] = pos[p * 3 + 0]; ys[s] = pos[p * 3 + 1]; zs[s] = pos[p * 3 + 2];
    }
    __syncthreads();
    for (int s = lane; s < BQ_TILE; s += 64) {
      float dx = xs[s] - cx, dy = ys[s] - cy, dz = zs[s] - cz;
      float d2 = __fadd_rn(__fadd_rn(__fmul_rn(dx, dx), __fmul_rn(dy, dy)), __fmul_rn(dz, dz));
      bool in = (d2 <= R2V);
      unsigned long long mask = __ballot(in);
      if (in) {
        int p = cnt + __popcll(mask & ((1ull << lane) - 1ull));
        if (p < BQ_CAP) { d2l[wv * BQ_CAP + p] = d2; jl[wv * BQ_CAP + p] = T * BQ_TILE + s; }
      }
      cnt += __popcll(mask);
    }
  }
  int n = min(cnt, BQ_CAP);
  int ks = min(KNB, n);
  float lv = -1.0f; int lj = -1;
  for (int it = 0; it < ks; ++it) {
    float mv = 3.4e38f; int mj = 0x7fffffff;
    for (int s = lane; s < n; s += 64) {
      float v = d2l[wv * BQ_CAP + s]; int j = jl[wv * BQ_CAP + s];
      bool newer = (v > lv) || (v == lv && j > lj);
      if (newer && (v < mv || (v == mv && j < mj))) { mv = v; mj = j; }
    }
#pragma unroll
    for (int off = 32; off >= 1; off >>= 1) {
      float ov = __shfl_xor(mv, off, 64);
      int   oj = __shfl_xor(mj, off, 64);
      if (ov < mv || (ov == mv && oj < mj)) { mv = ov; mj = oj; }
    }
    if (lane == 0) nbr[c * NPAD + it] = cbase + mj;
    lv = mv; lj = mj;
  }
  if (lane == 0) cntsel[c] = ks;
}

// ---------------------------------------------------------------------------
// Kernel 3: fused layer1 (35->128) + layer2 (128->256) + masked max-agg.
// 2 centroids per block, 320 threads. r16 counters showed 68.8M LDS bank
// conflict cycles from og*8-stride weight reads (per-lane stride 32B -> only
// 4 of 8 LDS 16B-slots covered). Fix: split each thread's 8-col tile into
// two 4-col halves at og*4 and HALF+og*4 (per-lane stride 16B = optimal).
// ---------------------------------------------------------------------------
__global__ __launch_bounds__(320) void fused_kernel(const float* __restrict__ x,
    const float* __restrict__ pos, const int* __restrict__ idxg,
    const int* __restrict__ nbr, const int* __restrict__ cnts,
    const float* __restrict__ lw1, const float* __restrict__ lb1,
    const float* __restrict__ lw2, const float* __restrict__ lb2,
    float* __restrict__ agg) {
  __shared__ float h1s[80 * 132];      // 42.2 KB
  __shared__ float wt[16 * 256];       // 16 KB (union: wx stage 32x128 in phase1)
  __shared__ float xr[80 * 36];        // 11.5 KB
  __shared__ float wr[4 * 128];        // lw1 rows 32..34 + lb1
  __shared__ float dpx[80], dpy[80], dpz[80];
  __shared__ int   jg[80];
  __shared__ float pcs[6];
  __shared__ int   cns[2];
  __shared__ unsigned aggL[512];
  const int t = threadIdx.x;
  const int c0 = blockIdx.x * 2;

  // phase 0: metadata + small weights + agg init
  if (t < 2) {
    int c = c0 + t; int ci = idxg[c];
    pcs[t * 3 + 0] = pos[ci * 3 + 0];
    pcs[t * 3 + 1] = pos[ci * 3 + 1];
    pcs[t * 3 + 2] = pos[ci * 3 + 2];
    cns[t] = cnts[c];
  }
  for (int i = t; i < 512; i += 320) {
    wr[i] = (i < 384) ? lw1[32 * 128 + i] : lb1[i - 384];
    aggL[i] = 0u;
  }
  __syncthreads();
  if (t < 80) {
    int r = t; int cc = (r >= 40) ? 1 : 0; int e = r - cc * 40;
    int j = -1;
    if (e < cns[cc]) {
      j = nbr[(c0 + cc) * NPAD + e];
      dpx[r] = pos[j * 3 + 0] - pcs[cc * 3 + 0];
      dpy[r] = pos[j * 3 + 1] - pcs[cc * 3 + 1];
      dpz[r] = pos[j * 3 + 2] - pcs[cc * 3 + 2];
    } else { dpx[r] = 0.f; dpy[r] = 0.f; dpz[r] = 0.f; }
    jg[r] = j;
  }
  __syncthreads();
  // stage x rows (zero for invalid) + wx (= lw1[0:32][:]) into wt
  for (int i = t; i < 640; i += 320) {
    int r = i >> 3, q = i & 7;
    int j = jg[r];
    float4 v = make_float4(0.f, 0.f, 0.f, 0.f);
    if (j >= 0) v = *(const float4*)&x[j * CCH + q * 4];
    *(float4*)&xr[r * 36 + q * 4] = v;
  }
  for (int i = t; i < 1024; i += 320) {
    *(float4*)&wt[i * 4] = *(const float4*)&lw1[i * 4];
  }
  __syncthreads();

  // phase 1: h1 = relu(xr@wx + dpos@wr + lb1). 4 rows x (4+4 split cols)/thread.
  {
    const int rg = t >> 4;      // 0..19
    const int og = t & 15;      // 0..15: cols og*4.. and 64+og*4..
    float4 a0[4], a1[4];
#pragma unroll
    for (int i = 0; i < 4; ++i) { a0[i] = make_float4(0, 0, 0, 0); a1[i] = make_float4(0, 0, 0, 0); }
#pragma unroll
    for (int kq = 0; kq < 8; ++kq) {
      float4 xv[4];
#pragma unroll
      for (int i = 0; i < 4; ++i) xv[i] = *(const float4*)&xr[(rg * 4 + i) * 36 + kq * 4];
#pragma unroll
      for (int kk = 0; kk < 4; ++kk) {
        float4 w0 = *(const float4*)&wt[(kq * 4 + kk) * 128 + og * 4];
        float4 w1 = *(const float4*)&wt[(kq * 4 + kk) * 128 + 64 + og * 4];
#pragma unroll
        for (int i = 0; i < 4; ++i) {
          float s = get4(xv[i], kk);
          FMA4(a0[i], s, w0);
          FMA4(a1[i], s, w1);
        }
      }
    }
#pragma unroll
    for (int i = 0; i < 4; ++i) {
      int r = rg * 4 + i;
      float dx = dpx[r], dy = dpy[r], dz = dpz[r];
#pragma unroll
      for (int j = 0; j < 4; ++j) {
        int o0 = og * 4 + j, o1 = 64 + og * 4 + j;
        float v0 = get4(a0[i], j) + dx * wr[o0] + dy * wr[128 + o0] + dz * wr[256 + o0] + wr[384 + o0];
        float v1 = get4(a1[i], j) + dx * wr[o1] + dy * wr[128 + o1] + dz * wr[256 + o1] + wr[384 + o1];
        h1s[r * 132 + o0] = fmaxf(v0, 0.0f);
        h1s[r * 132 + o1] = fmaxf(v1, 0.0f);
      }
    }
  }
  __syncthreads();

  // phase 2: h2 = h1s[80x128] @ lw2[128x256]. 8 rows x (4+4 split cols)/thread.
  const int og2 = t & 31;   // cols og2*4.. and 128+og2*4..
  const int eg = t >> 5;    // rows eg*8
  float4 c0v[8], c1v[8];
#pragma unroll
  for (int i = 0; i < 8; ++i) { c0v[i] = make_float4(0, 0, 0, 0); c1v[i] = make_float4(0, 0, 0, 0); }
  for (int kt = 0; kt < 8; ++kt) {
    __syncthreads();
    for (int i = t; i < 1024; i += 320) {
      *(float4*)&wt[i * 4] = *(const float4*)&lw2[kt * 4096 + i * 4];
    }
    __syncthreads();
#pragma unroll
    for (int kq = 0; kq < 4; ++kq) {
      float4 h4[8];
#pragma unroll
      for (int i = 0; i < 8; ++i)
        h4[i] = *(const float4*)&h1s[(eg * 8 + i) * 132 + kt * 16 + kq * 4];
#pragma unroll
      for (int kk = 0; kk < 4; ++kk) {
        float4 wa = *(const float4*)&wt[(kq * 4 + kk) * 256 + og2 * 4];
        float4 wb = *(const float4*)&wt[(kq * 4 + kk) * 256 + 128 + og2 * 4];
#pragma unroll
        for (int i = 0; i < 8; ++i) {
          float hv = get4(h4[i], kk);
          FMA4(c0v[i], hv, wa);
          FMA4(c1v[i], hv, wb);
        }
      }
    }
  }

  // phase 3: bias + relu + masked max into LDS (uint bits, values >= 0)
  {
    int cc = (eg >= 5) ? 1 : 0;
    int ebase = eg * 8 - cc * 40;
    int n = cns[cc];
#pragma unroll
    for (int j = 0; j < 4; ++j) {
      int o0 = og2 * 4 + j, o1 = 128 + og2 * 4 + j;
      float bias0 = lb2[o0], bias1 = lb2[o1];
      float mx0 = -1.0f, mx1 = -1.0f;
#pragma unroll
      for (int i = 0; i < 8; ++i) {
        if (ebase + i < n) {
          float v0 = fmaxf(get4(c0v[i], j) + bias0, 0.0f);
          float v1 = fmaxf(get4(c1v[i], j) + bias1, 0.0f);
          mx0 = fmaxf(mx0, v0);
          mx1 = fmaxf(mx1, v1);
        }
      }
      if (mx0 >= 0.0f) atomicMax(&aggL[cc * 256 + o0], __float_as_uint(mx0));
      if (mx1 >= 0.0f) atomicMax(&aggL[cc * 256 + o1], __float_as_uint(mx1));
    }
  }
  __syncthreads();
  for (int i = t; i < 512; i += 320) {
    agg[c0 * 256 + i] = __uint_as_float(aggL[i]);
  }
}

// ---------------------------------------------------------------------------
// Kernel 4: out = relu(agg @ gw1 + gb1). 64 rows x 256 cols per block.
// Split-column tile (og*4, 128+og*4) for conflict-free wt reads.
// ---------------------------------------------------------------------------
__global__ __launch_bounds__(256) void l3_kernel(const float* __restrict__ agg,
    const float* __restrict__ gw1, const float* __restrict__ gb1,
    float* __restrict__ out) {
  __shared__ float at[32 * 68];
  __shared__ float wt[32 * 256];
  const int t = threadIdx.x;
  const int row0 = blockIdx.x * 64;
  const int og = t & 31, rg = t >> 5;
  float4 c0v[8], c1v[8];
#pragma unroll
  for (int i = 0; i < 8; ++i) { c0v[i] = make_float4(0, 0, 0, 0); c1v[i] = make_float4(0, 0, 0, 0); }
  for (int kt = 0; kt < 8; ++kt) {
    __syncthreads();
    for (int i = t; i < 2048; i += 256) {
      int k = i & 31, r = i >> 5;
      at[k * 68 + r] = agg[(row0 + r) * 256 + kt * 32 + k];
    }
    for (int i = t; i < 2048; i += 256) {
      *(float4*)&wt[i * 4] = *(const float4*)&gw1[kt * 8192 + i * 4];
    }
    __syncthreads();
#pragma unroll
    for (int kq = 0; kq < 8; ++kq) {
#pragma unroll
      for (int kk = 0; kk < 4; ++kk) {
        int k = kq * 4 + kk;
        float4 av0 = *(const float4*)&at[k * 68 + rg * 8];
        float4 av1 = *(const float4*)&at[k * 68 + rg * 8 + 4];
        float4 wa = *(const float4*)&wt[k * 256 + og * 4];
        float4 wb = *(const float4*)&wt[k * 256 + 128 + og * 4];
#pragma unroll
        for (int i = 0; i < 8; ++i) {
          float hv = (i < 4) ? get4(av0, i) : get4(av1, i - 4);
          FMA4(c0v[i], hv, wa);
          FMA4(c1v[i], hv, wb);
        }
      }
    }
  }
  float4 b0 = *(const float4*)&gb1[og * 4];
  float4 b1 = *(const float4*)&gb1[128 + og * 4];
#pragma unroll
  for (int i = 0; i < 8; ++i) {
    float4 v0, v1;
    v0.x = fmaxf(c0v[i].x + b0.x, 0.f); v0.y = fmaxf(c0v[i].y + b0.y, 0.f);
    v0.z = fmaxf(c0v[i].z + b0.z, 0.f); v0.w = fmaxf(c0v[i].w + b0.w, 0.f);
    v1.x = fmaxf(c1v[i].x + b1.x, 0.f); v1.y = fmaxf(c1v[i].y + b1.y, 0.f);
    v1.z = fmaxf(c1v[i].z + b1.z, 0.f); v1.w = fmaxf(c1v[i].w + b1.w, 0.f);
    int row = row0 + rg * 8 + i;
    *(float4*)&out[row * 256 + og * 4] = v0;
    *(float4*)&out[row * 256 + 128 + og * 4] = v1;
  }
}

extern "C" void kernel_launch(void* const* d_in, const int* in_sizes, int n_in,
                              void* d_out, int out_size, void* d_ws, size_t ws_size,
                              hipStream_t stream) {
  (void)in_sizes; (void)n_in; (void)out_size; (void)ws_size;
  const float* x   = (const float*)d_in[0];
  const float* pos = (const float*)d_in[1];
  const float* lw1 = (const float*)d_in[3];
  const float* lb1 = (const float*)d_in[4];
  const float* lw2 = (const float*)d_in[5];
  const float* lb2 = (const float*)d_in[6];
  const float* gw1 = (const float*)d_in[7];
  const float* gb1 = (const float*)d_in[8];

  char* ws = (char*)d_ws;
  int*   idxg   = (int*)(ws + WS_IDX);
  int*   cnts   = (int*)(ws + WS_CNT);
  int*   nbr    = (int*)(ws + WS_NBR);
  float* agg    = (float*)(ws + WS_AGG);

  float* out0   = (float*)d_out;
  float* posd   = out0 + (size_t)M_TOT * HH3;
  float* batchf = posd + (size_t)M_TOT * 3;

  fps_kernel<<<dim3(NB), dim3(1024), 0, stream>>>(pos, idxg, posd, batchf);
  ballq_kernel<<<dim3(M_TOT / 4), dim3(256), 0, stream>>>(pos, idxg, nbr, cnts);
  fused_kernel<<<dim3(M_TOT / 2), dim3(320), 0, stream>>>(x, pos, idxg, nbr, cnts,
                                                          lw1, lb1, lw2, lb2, agg);
  l3_kernel<<<dim3(M_TOT / 64), dim3(256), 0, stream>>>(agg, gw1, gb1, out0);
}